// Round 10
// baseline (261.407 us; speedup 1.0000x reference)
//
#include <hip/hip_runtime.h>

typedef unsigned short u16;
typedef unsigned int u32;
typedef __attribute__((ext_vector_type(8))) short short8;
typedef __attribute__((ext_vector_type(4))) short s4v;
typedef __attribute__((ext_vector_type(4))) float f32x4;

#define S_LEN 2048
#define NH 16
#define HD 64
#define DM 1024

#if __has_builtin(__builtin_amdgcn_mfma_f32_16x16x16_bf16)
#define MFMA_K16(a, b, c) __builtin_amdgcn_mfma_f32_16x16x16_bf16(a, b, c, 0, 0, 0)
#else
#define MFMA_K16(a, b, c) __builtin_amdgcn_mfma_f32_16x16x16bf16_1k(a, b, c, 0, 0, 0)
#endif

__device__ __forceinline__ u16 f2bf(float f) {
    union { float f; u32 u; } v; v.f = f;
    u32 u = v.u;
    u32 r = u + 0x7fffu + ((u >> 16) & 1u);
    return (u16)(r >> 16);
}
__device__ __forceinline__ float bf2f(u16 h) {
    union { u32 u; float f; } v; v.u = ((u32)h) << 16;
    return v.f;
}
__device__ __forceinline__ u32 fbits(float f) {
    union { float f; u32 u; } v; v.f = f; return v.u;
}

__device__ __forceinline__ void load_lds16(const u16* g, u16* l) {
    __builtin_amdgcn_global_load_lds((const __attribute__((address_space(1))) void*)g,
                                     (__attribute__((address_space(3))) void*)l, 16, 0, 0);
}

// ---------------- fp32 -> bf16 convert (flat) ----------------
__global__ __launch_bounds__(256) void cvt_bf16(const float* __restrict__ in, u16* __restrict__ out, int n) {
    int i = (blockIdx.x * 256 + threadIdx.x) * 4;
    if (i < n) {
        float4 v = *(const float4*)(in + i);
        ushort4 o;
        o.x = f2bf(v.x); o.y = f2bf(v.y); o.z = f2bf(v.z); o.w = f2bf(v.w);
        *(ushort4*)(out + i) = o;
    }
}

// ---------------- 4x W [K][N] fp32 -> Wt [N][K] bf16 (one launch) ----------------
__global__ __launch_bounds__(256) void transpose_w4(const float* __restrict__ W0, const float* __restrict__ W1,
                                                    const float* __restrict__ W2, const float* __restrict__ W3,
                                                    u16* __restrict__ T0, u16* __restrict__ T1,
                                                    u16* __restrict__ T2, u16* __restrict__ T3) {
    __shared__ float tile[32][33];
    int z = blockIdx.z;
    const float* W = (z == 0) ? W0 : (z == 1) ? W1 : (z == 2) ? W2 : W3;
    u16* Wt = (z == 0) ? T0 : (z == 1) ? T1 : (z == 2) ? T2 : T3;
    int tx = threadIdx.x, ty = threadIdx.y;           // 32 x 8
    int k0 = blockIdx.y * 32, n0 = blockIdx.x * 32;
    #pragma unroll
    for (int j = 0; j < 32; j += 8)
        tile[ty + j][tx] = W[(size_t)(k0 + ty + j) * DM + n0 + tx];
    __syncthreads();
    #pragma unroll
    for (int j = 0; j < 32; j += 8)
        Wt[(size_t)(n0 + ty + j) * DM + k0 + tx] = f2bf(tile[tx][ty + j]);
}

// ---------------- 128xBN GEMM, BK=32, global_load_lds staging ----------------
// MODE 0 (NI=4): QKV fused (N=3072): Q/K RoPE fused; V head-major. MODE 1: fp32 out.
template<int MODE, int NI>   // BN = NI*32
__global__ __launch_bounds__(256) void gemm128(const u16* __restrict__ A, const u16* __restrict__ Bt,
                                               u16* __restrict__ Qh, u16* __restrict__ Kh,
                                               u16* __restrict__ Vh, float* __restrict__ Cf) {
    __shared__ u16 Al[128 * 32];
    __shared__ u16 Bl[NI * 32 * 32];
    const int K = DM;
    int tid = threadIdx.x;
    int wave = tid >> 6, lane = tid & 63, g = lane >> 4, ln = lane & 15;
    int wm = (wave >> 1) * 64, wn = (wave & 1) * (NI * 16);
    size_t mb0 = (size_t)blockIdx.y * 128, nb0 = (size_t)blockIdx.x * (NI * 32);

    f32x4 acc[4][NI];
    #pragma unroll
    for (int i = 0; i < 4; i++)
        #pragma unroll
        for (int j = 0; j < NI; j++)
            acc[i][j] = (f32x4){0.f, 0.f, 0.f, 0.f};

    const u16* Ag = A + (mb0 + wave * 32 + (lane >> 2)) * K + (lane & 3) * 8;
    u16* Alw = Al + wave * 1024;
    const u16* Bg;
    u16* Blw;
    if (NI == 4) {
        Bg = Bt + (nb0 + wave * 32 + (lane >> 2)) * K + (lane & 3) * 8;
        Blw = Bl + wave * 1024;
    } else {
        Bg = Bt + (nb0 + wave * 16 + (lane >> 2)) * K + (lane & 3) * 8;
        Blw = Bl + wave * 512;
    }

    for (int k0 = 0; k0 < K; k0 += 32) {
        __syncthreads();
        #pragma unroll
        for (int c = 0; c < 2; c++)
            load_lds16(Ag + (size_t)c * 16 * K + k0, Alw + c * 512);
        if (NI == 4) {
            #pragma unroll
            for (int c = 0; c < 2; c++)
                load_lds16(Bg + (size_t)c * 16 * K + k0, Blw + c * 512);
        } else {
            load_lds16(Bg + k0, Blw);
        }
        __syncthreads();
        short8 af[4], bf[NI];
        #pragma unroll
        for (int i = 0; i < 4; i++)
            af[i] = *(const short8*)&Al[(wm + i * 16 + ln) * 32 + g * 8];
        #pragma unroll
        for (int i = 0; i < NI; i++)
            bf[i] = *(const short8*)&Bl[(wn + i * 16 + ln) * 32 + g * 8];
        #pragma unroll
        for (int mi = 0; mi < 4; mi++)
            #pragma unroll
            for (int ni = 0; ni < NI; ni++)
                acc[mi][ni] = __builtin_amdgcn_mfma_f32_16x16x32_bf16(af[mi], bf[ni], acc[mi][ni], 0, 0, 0);
    }

    if (MODE == 1) {
        #pragma unroll
        for (int mi = 0; mi < 4; mi++)
            #pragma unroll
            for (int ni = 0; ni < NI; ni++)
                #pragma unroll
                for (int r = 0; r < 4; r++) {
                    int m = (int)mb0 + wm + mi * 16 + g * 4 + r;
                    int n = (int)nb0 + wn + ni * 16 + ln;
                    Cf[(size_t)m * DM + n] = acc[mi][ni][r];
                }
    } else {
        int nbase = (int)nb0 + wn;              // wave-uniform
        int which = nbase >> 10;
        int h = (nbase & (DM - 1)) >> 6;
        if (which < 2) {
            u16* dst = (which == 0) ? Qh : Kh;
            float inv0 = exp2f(-0.4152408746976557f * (float)ln);
            float inv1 = exp2f(-0.4152408746976557f * (float)(16 + ln));
            #pragma unroll
            for (int mi = 0; mi < 4; mi++) {
                #pragma unroll
                for (int r = 0; r < 4; r++) {
                    int m = (int)mb0 + wm + mi * 16 + g * 4 + r;
                    int b = m >> 11, s = m & (S_LEN - 1);
                    float fs = (float)s;
                    float sn0, cs0, sn1, cs1;
                    __sincosf(fs * inv0, &sn0, &cs0);
                    __sincosf(fs * inv1, &sn1, &cs1);
                    float a0 = acc[mi][0][r], a1 = acc[mi][1][r];
                    float a2 = acc[mi][2][r], a3 = acc[mi][3][r];
                    size_t base = ((size_t)(b * NH + h) * S_LEN + s) * HD;
                    dst[base + ln]      = f2bf(a0 * cs0 - a2 * sn0);
                    dst[base + 16 + ln] = f2bf(a1 * cs1 - a3 * sn1);
                    dst[base + 32 + ln] = f2bf(a0 * sn0 + a2 * cs0);
                    dst[base + 48 + ln] = f2bf(a1 * sn1 + a3 * cs1);
                }
            }
        } else {
            #pragma unroll
            for (int mi = 0; mi < 4; mi++) {
                #pragma unroll
                for (int r = 0; r < 4; r++) {
                    int m = (int)mb0 + wm + mi * 16 + g * 4 + r;
                    int b = m >> 11, s = m & (S_LEN - 1);
                    size_t base = ((size_t)(b * NH + h) * S_LEN + s) * HD;
                    #pragma unroll
                    for (int ni = 0; ni < 4; ni++)
                        Vh[base + ni * 16 + ln] = f2bf(acc[mi][ni][r]);
                }
            }
        }
    }
}

// ---------------- V transpose: [BH][S][HD] -> [BH][HD][S] ----------------
__global__ __launch_bounds__(256) void vtrans(const u16* __restrict__ Vh, u16* __restrict__ Vt) {
    __shared__ u16 t[64][70];
    int tid = threadIdx.x;
    int s0 = blockIdx.x * 64, bh = blockIdx.y;
    int r = tid >> 2, c = (tid & 3) * 8;
    const u16* src = Vh + ((size_t)bh * S_LEN + s0) * HD;
    *(short8*)&t[r][c]      = *(const short8*)(src + (size_t)r * HD + c);
    *(short8*)&t[r][c + 32] = *(const short8*)(src + (size_t)r * HD + c + 32);
    __syncthreads();
    u16* dst = Vt + ((size_t)bh * HD + r) * S_LEN + s0;
    short8 o0, o1;
    #pragma unroll
    for (int j = 0; j < 8; j++) {
        o0[j] = (short)t[c + j][r];
        o1[j] = (short)t[c + 32 + j][r];
    }
    *(short8*)(dst + c)      = o0;
    *(short8*)(dst + c + 32) = o1;
}

// ---------------- Flash attention: S^T form, in-register P, dbuf LDS, K-split=4 ----------------
// S^T = K*Q^T -> P^T C-layout == B-operand of 16x16x16 MFMA -> PV from registers.
// K/V LDS double-buffered (XOR-swizzled); global loads for tile t+4 issued at step top,
// ds_write to alt buffer at step end, ONE barrier per step.
// Epilogue: per-wave LDS transpose (reuses Kbuf) -> coalesced Op[bh][q][d] stores.
__global__ __launch_bounds__(512, 8) void flash_kernel(const u16* __restrict__ Qh, const u16* __restrict__ Kh,
                                                       const u16* __restrict__ Vt, const float* __restrict__ amask,
                                                       u16* __restrict__ Op0, u16* __restrict__ Op1,
                                                       u16* __restrict__ Op2, u16* __restrict__ Op3,
                                                       float* __restrict__ L0, float* __restrict__ L1,
                                                       float* __restrict__ L2, float* __restrict__ L3) {
    __shared__ u16 Kbuf[2][4096];
    __shared__ u16 Vbuf[2][4096];
    __shared__ float Ml[2][64];
    int tid = threadIdx.x;
    int wave = tid >> 6, lane = tid & 63, g = lane >> 4, ln = lane & 15;
    int qblk = 15 - ((int)blockIdx.x >> 2);
    int sp = blockIdx.x & 3;
    int bh = blockIdx.y;
    int q0 = qblk * 128 + wave * 16;
    int qv = q0 + ln;
    const u16* Qb = Qh + (size_t)bh * (S_LEN * HD);
    const u16* Kb = Kh + (size_t)bh * (S_LEN * HD);
    const u16* Vb = Vt + (size_t)bh * (S_LEN * HD);
    const float* am = amask + (bh >> 4) * S_LEN;

    short8 qa0 = *(const short8*)(Qb + (size_t)(q0 + ln) * HD + g * 8);
    short8 qa1 = *(const short8*)(Qb + (size_t)(q0 + ln) * HD + 32 + g * 8);

    f32x4 O[4];
    #pragma unroll
    for (int i = 0; i < 4; i++) O[i] = (f32x4){0.f, 0.f, 0.f, 0.f};
    float lsum = 0.f;
    const float SCL = 0.125f * 1.4426950408889634f;       // scale * log2(e)
    const float MSCL = -1.4426950408889634e9f;            // -1e9 * log2(e)

    int T = 2 * qblk + 2;
    // staging: 512 threads, each 1 K-b128 + 1 V-b128, XOR-swizzled stride-64 LDS
    int srow = tid >> 3, scid = tid & 7, s7 = srow & 7;
    int swoff = srow * 64 + ((scid ^ s7) * 8);
    const u16* KgP = Kb + (size_t)srow * HD + scid * 8;
    const u16* VgP = Vb + (size_t)srow * S_LEN + scid * 8;

    // loop-invariant swizzled frag offsets
    int l7 = ln & 7;
    int kc0 = (g ^ l7) * 8;                 // K frag cols 0..31
    int kc1 = ((4 + g) ^ l7) * 8;           // K frag cols 32..63
    int rbq = ln * 64;                      // row base within 16-row sub-tile
    int vcoff[4];
    #pragma unroll
    for (int n0 = 0; n0 < 4; n0++)
        vcoff[n0] = (((n0 * 2 + (g >> 1)) ^ l7) * 8) + ((g & 1) * 4);

    // preload first tile -> buf 0
    {
        int kb0 = sp * 64;
        *(short8*)&Kbuf[0][swoff] = *(const short8*)(KgP + (size_t)kb0 * HD);
        *(short8*)&Vbuf[0][swoff] = *(const short8*)(VgP + kb0);
        if (tid < 64) Ml[0][tid] = (1.0f - am[kb0 + tid]) * MSCL;
    }
    __syncthreads();
    int cur = 0;

    for (int kt = sp; kt < T; kt += 4) {
        int kbase = kt * 64;
        int knext = (kt + 4 < T) ? kbase + 256 : kbase;
        // prefetch next tile into registers (latency overlaps this step's compute)
        short8 pk = *(const short8*)(KgP + (size_t)knext * HD);
        short8 pv = *(const short8*)(VgP + knext);
        float pm = am[knext + (tid & 63)];

        bool needmask = (kbase + 63 > q0);
        u32 pkk[4][2];

        // ---- S^T = K*Q^T, exp2, pack P^T into registers (v_perm truncation) ----
        #pragma unroll
        for (int n0 = 0; n0 < 4; n0++) {
            const u16* kr = &Kbuf[cur][n0 * 1024 + rbq];
            short8 kb0 = *(const short8*)(kr + kc0);
            short8 kb1 = *(const short8*)(kr + kc1);
            f32x4 sv = (f32x4){0.f, 0.f, 0.f, 0.f};
            sv = __builtin_amdgcn_mfma_f32_16x16x32_bf16(kb0, qa0, sv, 0, 0, 0);
            sv = __builtin_amdgcn_mfma_f32_16x16x32_bf16(kb1, qa1, sv, 0, 0, 0);
            f32x4 mkv = *(f32x4*)&Ml[cur][n0 * 16 + g * 4];
            int keyb = kbase + n0 * 16 + g * 4;
            float p[4];
            #pragma unroll
            for (int r = 0; r < 4; r++) {
                float s2 = sv[r] * SCL + mkv[r];
                if (needmask && (keyb + r > qv)) s2 = -1.0e9f;
                p[r] = exp2f(s2);
                lsum += p[r];
            }
            pkk[n0][0] = __builtin_amdgcn_perm(fbits(p[1]), fbits(p[0]), 0x07060302u);
            pkk[n0][1] = __builtin_amdgcn_perm(fbits(p[3]), fbits(p[2]), 0x07060302u);
        }

        // ---- O^T += V^T * P^T : P from registers, V^T b64 frags from LDS ----
        #pragma unroll
        for (int t = 0; t < 4; t++) {
            const u16* vr = &Vbuf[cur][t * 1024 + rbq];
            #pragma unroll
            for (int n0 = 0; n0 < 4; n0++) {
                s4v va = *(const s4v*)(vr + vcoff[n0]);
                union { u32 u[2]; s4v v; } pb;
                pb.u[0] = pkk[n0][0];
                pb.u[1] = pkk[n0][1];
                O[t] = MFMA_K16(va, pb.v, O[t]);
            }
        }

        // ---- stage prefetched tile into alt buffer, single barrier ----
        *(short8*)&Kbuf[cur ^ 1][swoff] = pk;
        *(short8*)&Vbuf[cur ^ 1][swoff] = pv;
        if (tid < 64) Ml[cur ^ 1][tid] = (1.0f - pm) * MSCL;
        __syncthreads();
        cur ^= 1;
    }

    // ---- epilogue: lsum (2 shuffles), per-wave LDS transpose of O, coalesced store ----
    lsum += __shfl_xor(lsum, 16, 64);
    lsum += __shfl_xor(lsum, 32, 64);
    u16* Od = (sp == 0) ? Op0 : (sp == 1) ? Op1 : (sp == 2) ? Op2 : Op3;
    float* Ld = (sp == 0) ? L0 : (sp == 1) ? L1 : (sp == 2) ? L2 : L3;
    if (lane < 16) Ld[(size_t)bh * S_LEN + q0 + ln] = lsum;

    // per-wave 16q x 64d bf16 tile in Kbuf (2KB/wave), XOR-swizzled on 8-elem granules
    u16* Ow = ((u16*)Kbuf) + wave * 1024;
    #pragma unroll
    for (int t = 0; t < 4; t++)
        #pragma unroll
        for (int r = 0; r < 4; r++)
            Ow[ln * 64 + (((t * 2 + (g >> 1)) ^ l7) * 8) + (g & 1) * 4 + r] = f2bf(O[t][r]);
    // read rows, store coalesced: lane covers q=lane&15, d-granules (lane>>4)*2 + {0,1}
    int qr = lane & 15, dg = (lane >> 4) * 2, q7 = qr & 7;
    short8 r0 = *(const short8*)(Ow + qr * 64 + ((dg ^ q7) * 8));
    short8 r1 = *(const short8*)(Ow + qr * 64 + (((dg + 1) ^ q7) * 8));
    size_t obase = ((size_t)bh * S_LEN + q0 + qr) * HD;
    *(short8*)(Od + obase + dg * 8) = r0;
    *(short8*)(Od + obase + dg * 8 + 8) = r1;
}

// ---------------- Reduce: attn[b][q][h*64+d] = sum_sp Op[bh][q][d] / sum_sp L ----------------
__global__ __launch_bounds__(256) void flash_reduce(const u16* __restrict__ Op0, const u16* __restrict__ Op1,
                                                    const u16* __restrict__ Op2, const u16* __restrict__ Op3,
                                                    const float* __restrict__ L0, const float* __restrict__ L1,
                                                    const float* __restrict__ L2, const float* __restrict__ L3,
                                                    u16* __restrict__ attn) {
    int tid = threadIdx.x;
    int qt = blockIdx.x, bh = blockIdx.y;
    int b = bh >> 4, h = bh & (NH - 1);
    int q = qt * 64 + (tid >> 2);
    int dblk = (tid & 3) * 16;
    size_t li = (size_t)bh * S_LEN + q;
    float inv = 1.0f / (L0[li] + L1[li] + L2[li] + L3[li]);
    size_t off = ((size_t)bh * S_LEN + q) * HD + dblk;
    short8 a0 = *(const short8*)(Op0 + off), a0b = *(const short8*)(Op0 + off + 8);
    short8 a1 = *(const short8*)(Op1 + off), a1b = *(const short8*)(Op1 + off + 8);
    short8 a2 = *(const short8*)(Op2 + off), a2b = *(const short8*)(Op2 + off + 8);
    short8 a3 = *(const short8*)(Op3 + off), a3b = *(const short8*)(Op3 + off + 8);
    short8 o0, o1;
    #pragma unroll
    for (int j = 0; j < 8; j++) {
        o0[j] = (short)f2bf((bf2f((u16)a0[j]) + bf2f((u16)a1[j]) +
                             bf2f((u16)a2[j]) + bf2f((u16)a3[j])) * inv);
        o1[j] = (short)f2bf((bf2f((u16)a0b[j]) + bf2f((u16)a1b[j]) +
                             bf2f((u16)a2b[j]) + bf2f((u16)a3b[j])) * inv);
    }
    u16* dst = attn + ((size_t)b * S_LEN + q) * DM + h * HD + dblk;
    *(short8*)dst = o0;
    *(short8*)(dst + 8) = o1;
}

extern "C" void kernel_launch(void* const* d_in, const int* in_sizes, int n_in,
                              void* d_out, int out_size, void* d_ws, size_t ws_size,
                              hipStream_t stream) {
    const float* x     = (const float*)d_in[0];
    const float* amask = (const float*)d_in[1];
    const float* Wq    = (const float*)d_in[2];
    const float* Wk    = (const float*)d_in[3];
    const float* Wv    = (const float*)d_in[4];
    const float* Wo    = (const float*)d_in[5];
    float* out = (float*)d_out;
    char* ws = (char*)d_ws;

    // [0,8M):      x_bf (dead after gemm<0>) -> Op1
    // [8M,9.1M):   L0..L3 (overlaps Wqkv_t, dead after gemm<0>)
    // [8M,14.7M):  Wqkv_t
    // [14M,16.7M): Wo_t (alive to the end)
    // [16M,24M):   Qh   [24M,32M): Kh
    // [32M,40M):   Vt (dead after flash) -> attn_final
    // [40M,48M):   Vh (dead after vtrans) -> Op0
    // Op2/Op3 in d_out (16 MB fp32, only written by final gemm).
    u16* x_bf   = (u16*)(ws);
    u16* Op1    = (u16*)(ws);
    u16* Wqkv_t = (u16*)(ws + 8388608);
    float* L0   = (float*)(ws + 8388608);
    float* L1   = (float*)(ws + 8650752);
    float* L2   = (float*)(ws + 8912896);
    float* L3   = (float*)(ws + 9175040);
    u16* Wo_t   = (u16*)(ws + 14680064);
    u16* Qh     = (u16*)(ws + 16777216);
    u16* Kh     = (u16*)(ws + 25165824);
    u16* Vt     = (u16*)(ws + 33554432);
    u16* attnF  = (u16*)(ws + 33554432);           // over Vt, after flash
    u16* Vh     = (u16*)(ws + 41943040);
    u16* Op0    = (u16*)(ws + 41943040);           // over Vh, after vtrans
    u16* Op2    = (u16*)d_out;
    u16* Op3    = (u16*)d_out + 4194304;

    cvt_bf16<<<4096, 256, 0, stream>>>(x, x_bf, 2 * S_LEN * DM);

    transpose_w4<<<dim3(32, 32, 4), dim3(32, 8), 0, stream>>>(
        Wq, Wk, Wv, Wo, Wqkv_t, Wqkv_t + 1048576, Wqkv_t + 2097152, Wo_t);

    gemm128<0, 4><<<dim3(24, 32), 256, 0, stream>>>(x_bf, Wqkv_t, Qh, Kh, Vh, nullptr);

    vtrans<<<dim3(32, 2 * NH), 256, 0, stream>>>(Vh, Vt);

    flash_kernel<<<dim3(64, 2 * NH), 512, 0, stream>>>(Qh, Kh, Vt, amask,
                                                       Op0, Op1, Op2, Op3, L0, L1, L2, L3);

    flash_reduce<<<dim3(32, 2 * NH), 256, 0, stream>>>(Op0, Op1, Op2, Op3,
                                                       L0, L1, L2, L3, attnF);

    gemm128<1, 2><<<dim3(16, 32), 256, 0, stream>>>(attnF, Wo_t, nullptr, nullptr, nullptr, out);
}